// Round 1
// baseline (405.047 us; speedup 1.0000x reference)
//
#include <hip/hip_runtime.h>
#include <hip/hip_bf16.h>
#include <stdint.h>

#define D_MODEL 1024
#define HEAD_DIM 128
#define NUM_HEADS 8
#define SEQ 4096
#define NQKV 1280  // 1024 q | 128 k | 128 v

using bf16x8 = __attribute__((ext_vector_type(8))) short;
using f32x4  = __attribute__((ext_vector_type(4))) float;

__device__ __forceinline__ unsigned short f32_to_bf16(float f) {
    union { float f; uint32_t u; } c{f};
    uint32_t u = c.u;
    return (unsigned short)((u + 0x7fffu + ((u >> 16) & 1u)) >> 16);
}

// ---------------- kernel 0a: x fp32 -> bf16 ----------------
__global__ void cvt_x(const float4* __restrict__ x, ushort4* __restrict__ xb, int n4) {
    int i = blockIdx.x * blockDim.x + threadIdx.x;
    int stride = gridDim.x * blockDim.x;
    for (; i < n4; i += stride) {
        float4 v = x[i];
        ushort4 o;
        o.x = f32_to_bf16(v.x); o.y = f32_to_bf16(v.y);
        o.z = f32_to_bf16(v.z); o.w = f32_to_bf16(v.w);
        xb[i] = o;
    }
}

// ---------------- kernel 0b: pack W transposed, bf16 --------
// Wt[n][k] = W[k][n], n in [0,1280): 0-1023 q, 1024-1151 k, 1152-1279 v
__global__ void pack_wt(const float* __restrict__ Wq, const float* __restrict__ Wk,
                        const float* __restrict__ Wv, unsigned short* __restrict__ Wt) {
    int id = blockIdx.x * blockDim.x + threadIdx.x;
    if (id >= NQKV * D_MODEL) return;
    int nn = id / D_MODEL, k = id % D_MODEL;
    float v;
    if (nn < 1024)      v = Wq[k * 1024 + nn];
    else if (nn < 1152) v = Wk[k * 128 + (nn - 1024)];
    else                v = Wv[k * 128 + (nn - 1152)];
    Wt[id] = f32_to_bf16(v);
}

// ---------------- kernel 1: QKV projection GEMM -------------
// C[4096][1280] = xb[4096][1024] @ W[1024][1280]; epilogue splits q/k/v.
// q pre-scaled by 1/sqrt(128); v stored transposed [128][4096].
__global__ __launch_bounds__(256) void qkv_gemm(
    const unsigned short* __restrict__ xb,   // [4096][1024]
    const unsigned short* __restrict__ Wt,   // [1280][1024]
    const float* __restrict__ bq, const float* __restrict__ bk, const float* __restrict__ bv,
    unsigned short* __restrict__ q_bf,       // [4096][1024]
    unsigned short* __restrict__ k_bf,       // [4096][128]
    unsigned short* __restrict__ vt_bf)      // [128][4096]
{
    __shared__ unsigned short As[128 * 72];  // ld 72: 144B row, 16B-aligned, 2-way banks (free)
    __shared__ unsigned short Bs[128 * 72];
    const int t = threadIdx.x;
    const int lane = t & 63, wave = t >> 6;
    const int l15 = lane & 15, quad = lane >> 4;
    const int m0 = blockIdx.y * 128, n0 = blockIdx.x * 128;
    const int wm = (wave >> 1) * 64, wn = (wave & 1) * 64;

    f32x4 acc[4][4];
#pragma unroll
    for (int i = 0; i < 4; ++i)
#pragma unroll
        for (int j = 0; j < 4; ++j) acc[i][j] = (f32x4)0.0f;

    for (int k0 = 0; k0 < 1024; k0 += 64) {
        __syncthreads();
#pragma unroll
        for (int p = 0; p < 4; ++p) {
            int r = (t >> 3) + p * 32;      // 0..127
            int c = (t & 7) * 8;            // 0..56
            *(int4*)&As[r * 72 + c] = *(const int4*)&xb[(m0 + r) * 1024 + k0 + c];
            *(int4*)&Bs[r * 72 + c] = *(const int4*)&Wt[(n0 + r) * 1024 + k0 + c];
        }
        __syncthreads();
#pragma unroll
        for (int ks = 0; ks < 2; ++ks) {
            bf16x8 a[4], b[4];
#pragma unroll
            for (int mt = 0; mt < 4; ++mt)
                a[mt] = *(const bf16x8*)&As[(wm + mt * 16 + l15) * 72 + ks * 32 + quad * 8];
#pragma unroll
            for (int nt = 0; nt < 4; ++nt)
                b[nt] = *(const bf16x8*)&Bs[(wn + nt * 16 + l15) * 72 + ks * 32 + quad * 8];
#pragma unroll
            for (int mt = 0; mt < 4; ++mt)
#pragma unroll
                for (int nt = 0; nt < 4; ++nt)
                    acc[mt][nt] = __builtin_amdgcn_mfma_f32_16x16x32_bf16(a[mt], b[nt], acc[mt][nt], 0, 0, 0);
        }
    }

    const float qscale = 0.08838834764831843f;  // 1/sqrt(128)
#pragma unroll
    for (int mt = 0; mt < 4; ++mt)
#pragma unroll
        for (int nt = 0; nt < 4; ++nt)
#pragma unroll
            for (int r = 0; r < 4; ++r) {
                int row = m0 + wm + mt * 16 + quad * 4 + r;   // C/D: row=quad*4+reg
                int col = n0 + wn + nt * 16 + l15;            //      col=lane&15
                float v = acc[mt][nt][r];
                if (col < 1024)
                    q_bf[row * 1024 + col] = f32_to_bf16((v + bq[col]) * qscale);
                else if (col < 1152)
                    k_bf[row * 128 + (col - 1024)] = f32_to_bf16(v + bk[col - 1024]);
                else
                    vt_bf[(col - 1152) * 4096 + row] = f32_to_bf16(v + bv[col - 1152]);
            }
}

// ---------------- kernel 2: flash attention -----------------
// grid (64 q-tiles, 8 heads); block 256 = 4 waves; wave = 16 q-rows; key tiles of 64.
__global__ __launch_bounds__(256) void mqa_attn(
    const unsigned short* __restrict__ q_bf,   // [4096][1024] pre-scaled
    const unsigned short* __restrict__ k_bf,   // [4096][128]
    const unsigned short* __restrict__ vt_bf,  // [128][4096]
    float* __restrict__ out)                   // [4096][1024]
{
    __shared__ unsigned short Ks[64 * 136];    // [key][d], ld 136
    __shared__ unsigned short Vs[128 * 72];    // [d][key], ld 72
    __shared__ unsigned short Ps[4][16 * 72];  // per-wave P transpose buffer
    const int t = threadIdx.x;
    const int lane = t & 63, wave = t >> 6;
    const int l15 = lane & 15, quad = lane >> 4;
    const int h = blockIdx.y;
    const int q0 = blockIdx.x * 64;

    // Q fragments, A-operand layout: A[m=lane&15][k=quad*8+j]
    bf16x8 qf[4];
    {
        int qrow = q0 + wave * 16 + l15;
#pragma unroll
        for (int ks = 0; ks < 4; ++ks)
            qf[ks] = *(const bf16x8*)&q_bf[qrow * 1024 + h * 128 + ks * 32 + quad * 8];
    }

    f32x4 o[8];
#pragma unroll
    for (int d = 0; d < 8; ++d) o[d] = (f32x4)0.0f;
    float m_i[4], l_i[4];
#pragma unroll
    for (int r = 0; r < 4; ++r) { m_i[r] = -1e30f; l_i[r] = 0.0f; }

    for (int kt = 0; kt < SEQ; kt += 64) {
        __syncthreads();
        // stage K tile (64 keys x 128 d) — contiguous 16B chunks
#pragma unroll
        for (int p = 0; p < 4; ++p) {
            int r = (t >> 4) + p * 16;      // 0..63
            int c = (t & 15) * 8;           // 0..120
            *(int4*)&Ks[r * 136 + c] = *(const int4*)&k_bf[(kt + r) * 128 + c];
        }
        // stage Vt tile (128 d x 64 keys)
#pragma unroll
        for (int p = 0; p < 4; ++p) {
            int r = (t >> 3) + p * 32;      // 0..127
            int c = (t & 7) * 8;            // 0..56
            *(int4*)&Vs[r * 72 + c] = *(const int4*)&vt_bf[r * 4096 + kt + c];
        }
        __syncthreads();

        // S = Q K^T : B[k=d][n=key] -> lane reads K[key=nt*16+l15][d contiguous]
        f32x4 s[4];
#pragma unroll
        for (int nt = 0; nt < 4; ++nt) s[nt] = (f32x4)0.0f;
#pragma unroll
        for (int ks = 0; ks < 4; ++ks)
#pragma unroll
            for (int nt = 0; nt < 4; ++nt) {
                bf16x8 b = *(const bf16x8*)&Ks[(nt * 16 + l15) * 136 + ks * 32 + quad * 8];
                s[nt] = __builtin_amdgcn_mfma_f32_16x16x32_bf16(qf[ks], b, s[nt], 0, 0, 0);
            }

        // online softmax; row = quad*4 + r lives across the 16 lanes of this quad-group
        float p_v[4][4], alpha[4];
#pragma unroll
        for (int r = 0; r < 4; ++r) {
            float mx = fmaxf(fmaxf(s[0][r], s[1][r]), fmaxf(s[2][r], s[3][r]));
#pragma unroll
            for (int off = 1; off < 16; off <<= 1)
                mx = fmaxf(mx, __shfl_xor(mx, off, 64));
            float m_new = fmaxf(m_i[r], mx);
            alpha[r] = __expf(m_i[r] - m_new);
            m_i[r] = m_new;
            float rs = 0.0f;
#pragma unroll
            for (int nt = 0; nt < 4; ++nt) {
                float pv = __expf(s[nt][r] - m_new);
                p_v[nt][r] = pv;
                rs += pv;
            }
#pragma unroll
            for (int off = 1; off < 16; off <<= 1)
                rs += __shfl_xor(rs, off, 64);
            l_i[r] = l_i[r] * alpha[r] + rs;
        }
#pragma unroll
        for (int d = 0; d < 8; ++d)
#pragma unroll
            for (int r = 0; r < 4; ++r) o[d][r] *= alpha[r];

        // P: C-layout -> A-layout via per-wave LDS round-trip (m120 pattern)
        unsigned short* P = &Ps[wave][0];
#pragma unroll
        for (int nt = 0; nt < 4; ++nt)
#pragma unroll
            for (int r = 0; r < 4; ++r)
                P[(quad * 4 + r) * 72 + nt * 16 + l15] = f32_to_bf16(p_v[nt][r]);
        asm volatile("s_waitcnt lgkmcnt(0)" ::: "memory");

        // O += P V : A[m=qrow][k=key], B[k=key][n=d] from Vs[d][key]
#pragma unroll
        for (int ks = 0; ks < 2; ++ks) {
            bf16x8 a = *(const bf16x8*)&P[l15 * 72 + ks * 32 + quad * 8];
#pragma unroll
            for (int d = 0; d < 8; ++d) {
                bf16x8 b = *(const bf16x8*)&Vs[(d * 16 + l15) * 72 + ks * 32 + quad * 8];
                o[d] = __builtin_amdgcn_mfma_f32_16x16x32_bf16(a, b, o[d], 0, 0, 0);
            }
        }
    }

#pragma unroll
    for (int r = 0; r < 4; ++r) {
        float inv = 1.0f / l_i[r];
        int row = q0 + wave * 16 + quad * 4 + r;
#pragma unroll
        for (int d = 0; d < 8; ++d)
            out[row * 1024 + h * 128 + d * 16 + l15] = o[d][r] * inv;
    }
}

// ---------------- launch ------------------------------------
extern "C" void kernel_launch(void* const* d_in, const int* in_sizes, int n_in,
                              void* d_out, int out_size, void* d_ws, size_t ws_size,
                              hipStream_t stream) {
    const float* x  = (const float*)d_in[0];
    const float* Wq = (const float*)d_in[1];
    const float* bq = (const float*)d_in[2];
    const float* Wk = (const float*)d_in[3];
    const float* bk = (const float*)d_in[4];
    const float* Wv = (const float*)d_in[5];
    const float* bv = (const float*)d_in[6];
    float* out = (float*)d_out;

    char* ws = (char*)d_ws;
    unsigned short* xb = (unsigned short*)(ws);                    // 8 MB  [4096][1024]
    unsigned short* Wt = (unsigned short*)(ws + 8388608);          // 2.5MB [1280][1024]
    unsigned short* qb = (unsigned short*)(ws + 11010048);         // 8 MB  [4096][1024]
    unsigned short* kb = (unsigned short*)(ws + 19398656);         // 1 MB  [4096][128]
    unsigned short* vt = (unsigned short*)(ws + 20447232);         // 1 MB  [128][4096]
    // total ws use: 21495808 B

    cvt_x<<<1024, 256, 0, stream>>>((const float4*)x, (ushort4*)xb, SEQ * D_MODEL / 4);
    pack_wt<<<(NQKV * D_MODEL + 255) / 256, 256, 0, stream>>>(Wq, Wk, Wv, Wt);
    qkv_gemm<<<dim3(10, 32), 256, 0, stream>>>(xb, Wt, bq, bk, bv, qb, kb, vt);
    mqa_attn<<<dim3(SEQ / 64, NUM_HEADS), 256, 0, stream>>>(qb, kb, vt, out);
}